// Round 1
// baseline (968.892 us; speedup 1.0000x reference)
//
#include <hip/hip_runtime.h>
#include <math.h>

#define NN 50000
#define EE 800000
#define ET (EE + NN)
#define HID 128
#define NSTORE 50

// ---------------------------------------------------------------- CSR build
__global__ void k_count(const int* __restrict__ ei, const float* __restrict__ ew,
                        int* __restrict__ cnt, float* __restrict__ wsum) {
    int i = blockIdx.x * 256 + threadIdx.x;
    if (i >= EE) return;
    int dst = ei[EE + i];
    atomicAdd(&cnt[dst], 1);
    atomicAdd(&wsum[dst], ew[i]);
}

__global__ __launch_bounds__(1024) void k_scan(const int* __restrict__ cnt, int* __restrict__ offs) {
    __shared__ int part[1024];
    int t = threadIdx.x;
    const int C = (NN + 1023) / 1024;
    int lo = t * C, hi = min(NN, lo + C);
    int s = 0;
    for (int i = lo; i < hi; ++i) s += cnt[i] + 1;   // +1 for self loop
    part[t] = s;
    __syncthreads();
    for (int d = 1; d < 1024; d <<= 1) {
        int v = (t >= d) ? part[t - d] : 0;
        __syncthreads();
        part[t] += v;
        __syncthreads();
    }
    int base = (t == 0) ? 0 : part[t - 1];
    for (int i = lo; i < hi; ++i) { offs[i] = base; base += cnt[i] + 1; }
    if (t == 1023) offs[NN] = part[1023];
}

__global__ void k_scatter(const int* __restrict__ ei, const float* __restrict__ ew,
                          const int* __restrict__ offs, int* __restrict__ fill,
                          int* __restrict__ csr_src, float* __restrict__ csr_ea) {
    int i = blockIdx.x * 256 + threadIdx.x;
    if (i >= EE) return;
    int src = ei[i], dst = ei[EE + i];
    int pos = offs[dst] + atomicAdd(&fill[dst], 1);
    csr_src[pos] = src;
    csr_ea[pos] = ew[i];
}

__global__ void k_selfloop(const int* __restrict__ offs, const int* __restrict__ cnt,
                           const float* __restrict__ wsum,
                           int* __restrict__ csr_src, float* __restrict__ csr_ea) {
    int i = blockIdx.x * 256 + threadIdx.x;
    if (i >= NN) return;
    int pos = offs[i + 1] - 1;                        // last slot of segment
    csr_src[pos] = i;
    csr_ea[pos] = wsum[i] / fmaxf((float)cnt[i], 1.0f);
}

// ---------------------------------------------------------------- GEMM (fp32 tiled)
// out[n][128] = act(A[n][K] @ W[K][128] + bias), act: 0=none, 1=exact GELU
__global__ __launch_bounds__(256) void k_gemm(const float* __restrict__ A,
                                              const float* __restrict__ W,
                                              const float* __restrict__ bias,
                                              float* __restrict__ out,
                                              int n, int K, int act) {
    __shared__ float As[16][64];
    __shared__ float Bs[16][64];
    int tid = threadIdx.x;
    int tx = tid & 15, ty = tid >> 4;
    int row0 = blockIdx.x * 64, col0 = blockIdx.y * 64;
    float acc[4][4];
#pragma unroll
    for (int i = 0; i < 4; ++i)
#pragma unroll
        for (int j = 0; j < 4; ++j) acc[i][j] = 0.f;

    int am = tid >> 2;            // 0..63 row in tile
    int ak = (tid & 3) * 4;       // 0,4,8,12
    int bk = tid >> 4;            // 0..15
    int bj = (tid & 15) * 4;      // col in tile

    for (int k0 = 0; k0 < K; k0 += 16) {
        float4 av = make_float4(0.f, 0.f, 0.f, 0.f);
        int arow = row0 + am;
        if (arow < n) av = *(const float4*)(A + (size_t)arow * K + k0 + ak);
        As[ak + 0][am] = av.x; As[ak + 1][am] = av.y;
        As[ak + 2][am] = av.z; As[ak + 3][am] = av.w;
        float4 bv = *(const float4*)(W + (size_t)(k0 + bk) * HID + col0 + bj);
        Bs[bk][bj + 0] = bv.x; Bs[bk][bj + 1] = bv.y;
        Bs[bk][bj + 2] = bv.z; Bs[bk][bj + 3] = bv.w;
        __syncthreads();
#pragma unroll
        for (int kk = 0; kk < 16; ++kk) {
            float a[4], b[4];
#pragma unroll
            for (int i = 0; i < 4; ++i) a[i] = As[kk][ty * 4 + i];
#pragma unroll
            for (int j = 0; j < 4; ++j) b[j] = Bs[kk][tx * 4 + j];
#pragma unroll
            for (int i = 0; i < 4; ++i)
#pragma unroll
                for (int j = 0; j < 4; ++j) acc[i][j] += a[i] * b[j];
        }
        __syncthreads();
    }
#pragma unroll
    for (int i = 0; i < 4; ++i) {
        int r = row0 + ty * 4 + i;
        if (r >= n) continue;
#pragma unroll
        for (int j = 0; j < 4; ++j) {
            int c = col0 + tx * 4 + j;
            float v = acc[i][j] + bias[c];
            if (act == 1) v = 0.5f * v * (1.f + erff(v * 0.70710678118654752f));
            out[(size_t)r * HID + c] = v;
        }
    }
}

// ---------------------------------------------------------------- LayerNorm (wave per node, in place)
__global__ __launch_bounds__(256) void k_ln(float* __restrict__ h,
                                            const float* __restrict__ g,
                                            const float* __restrict__ b) {
    int wid = (blockIdx.x * 256 + threadIdx.x) >> 6;
    int lane = threadIdx.x & 63;
    if (wid >= NN) return;
    size_t base = (size_t)wid * HID;
    int d0 = lane * 2, d1 = d0 + 1;
    float v0 = h[base + d0], v1 = h[base + d1];
    float sm = v0 + v1, sq = v0 * v0 + v1 * v1;
#pragma unroll
    for (int k = 1; k < 64; k <<= 1) { sm += __shfl_xor(sm, k); sq += __shfl_xor(sq, k); }
    float mu = sm * (1.f / 128.f);
    float var = sq * (1.f / 128.f) - mu * mu;
    float r = rsqrtf(var + 1e-5f);
    h[base + d0] = (v0 - mu) * r * g[d0] + b[d0];
    h[base + d1] = (v1 - mu) * r * g[d1] + b[d1];
}

// ---------------------------------------------------------------- GATv2 attention, wave per dst node
// online softmax over CSR segment; fused +bias +residual +LayerNorm
__global__ __launch_bounds__(256) void k_attn(const float* __restrict__ xl,
                                              const float* __restrict__ xr,
                                              float* __restrict__ h,
                                              const int* __restrict__ offs,
                                              const int* __restrict__ csr_src,
                                              const float* __restrict__ csr_ea,
                                              const float* __restrict__ We,
                                              const float* __restrict__ att,
                                              const float* __restrict__ gbias,
                                              const float* __restrict__ g,
                                              const float* __restrict__ b) {
    int wid = (blockIdx.x * 256 + threadIdx.x) >> 6;
    int lane = threadIdx.x & 63;
    if (wid >= NN) return;
    int d0 = lane * 2, d1 = d0 + 1;
    size_t base = (size_t)wid * HID;
    float xr0 = xr[base + d0], xr1 = xr[base + d1];
    float a0 = att[d0], a1 = att[d1];
    float w0 = We[d0], w1 = We[d1];
    int p0 = offs[wid], p1 = offs[wid + 1];
    float m = -3.0e38f, Z = 0.f, acc0 = 0.f, acc1 = 0.f;
    for (int p = p0; p < p1; ++p) {
        int src = csr_src[p];
        float ea = csr_ea[p];
        const float* xls = xl + (size_t)src * HID;
        float xl0 = xls[d0], xl1 = xls[d1];
        float t0 = xl0 + xr0 + ea * w0;
        float t1 = xl1 + xr1 + ea * w1;
        t0 = (t0 > 0.f) ? t0 : 0.2f * t0;     // leaky_relu 0.2
        t1 = (t1 > 0.f) ? t1 : 0.2f * t1;
        float part = a0 * t0 + a1 * t1;
        part += __shfl_xor(part, 1);          // reduce 4 lanes of head
        part += __shfl_xor(part, 2);
        float nm = fmaxf(m, part);
        float s = __expf(m - nm);
        float w = __expf(part - nm);
        Z = Z * s + w;
        acc0 = acc0 * s + w * xl0;
        acc1 = acc1 * s + w * xl1;
        m = nm;
    }
    float inv = 1.f / (Z + 1e-16f);
    float o0 = acc0 * inv + gbias[d0] + h[base + d0];
    float o1 = acc1 * inv + gbias[d1] + h[base + d1];
    float sm = o0 + o1, sq = o0 * o0 + o1 * o1;
#pragma unroll
    for (int k = 1; k < 64; k <<= 1) { sm += __shfl_xor(sm, k); sq += __shfl_xor(sq, k); }
    float mu = sm * (1.f / 128.f);
    float var = sq * (1.f / 128.f) - mu * mu;
    float r = rsqrtf(var + 1e-5f);
    h[base + d0] = (o0 - mu) * r * g[d0] + b[d0];
    h[base + d1] = (o1 - mu) * r * g[d1] + b[d1];
}

// ---------------------------------------------------------------- per-store segment sum
__global__ __launch_bounds__(256) void k_store_sum(const float* __restrict__ h,
                                                   const int* __restrict__ mask,
                                                   float* __restrict__ ssum,
                                                   int* __restrict__ scnt) {
    __shared__ float ls[NSTORE * HID];
    __shared__ int lc[NSTORE];
    int t = threadIdx.x;
    for (int i = t; i < NSTORE * HID; i += 256) ls[i] = 0.f;
    if (t < NSTORE) lc[t] = 0;
    __syncthreads();
    int wid = blockIdx.x * 4 + (t >> 6);
    int lane = t & 63;
    int nw = gridDim.x * 4;
    int d0 = lane * 2, d1 = d0 + 1;
    for (int node = wid; node < NN; node += nw) {
        int s = mask[node];
        size_t base = (size_t)node * HID;
        atomicAdd(&ls[s * HID + d0], h[base + d0]);
        atomicAdd(&ls[s * HID + d1], h[base + d1]);
        if (lane == 0) atomicAdd(&lc[s], 1);
    }
    __syncthreads();
    for (int i = t; i < NSTORE * HID; i += 256) atomicAdd(&ssum[i], ls[i]);
    if (t < NSTORE) atomicAdd(&scnt[t], lc[t]);
}

// ---------------------------------------------------------------- gate: gm[s] = sigmoid(means@ctxW+ctxb)*means
__global__ __launch_bounds__(128) void k_gate(const float* __restrict__ ssum,
                                              const int* __restrict__ scnt,
                                              const float* __restrict__ ctxW,
                                              const float* __restrict__ ctxb,
                                              float* __restrict__ gm) {
    __shared__ float mloc[HID];
    int s = blockIdx.x, t = threadIdx.x;
    float c = fmaxf((float)scnt[s], 1.f);
    float mk = ssum[s * HID + t] / c;
    mloc[t] = mk;
    __syncthreads();
    float acc = ctxb[t];
    for (int j = 0; j < HID; ++j) acc += mloc[j] * ctxW[j * HID + t];
    float gate = 1.f / (1.f + __expf(-acc));
    gm[s * HID + t] = gate * mk;
}

// ---------------------------------------------------------------- final: out = LN(h + gm[store], fin_g, fin_b)
__global__ __launch_bounds__(256) void k_final(const float* __restrict__ h,
                                               const int* __restrict__ mask,
                                               const float* __restrict__ gm,
                                               const float* __restrict__ g,
                                               const float* __restrict__ b,
                                               float* __restrict__ out) {
    int wid = (blockIdx.x * 256 + threadIdx.x) >> 6;
    int lane = threadIdx.x & 63;
    if (wid >= NN) return;
    size_t base = (size_t)wid * HID;
    int s = mask[wid];
    int d0 = lane * 2, d1 = d0 + 1;
    float v0 = h[base + d0] + gm[s * HID + d0];
    float v1 = h[base + d1] + gm[s * HID + d1];
    float sm = v0 + v1, sq = v0 * v0 + v1 * v1;
#pragma unroll
    for (int k = 1; k < 64; k <<= 1) { sm += __shfl_xor(sm, k); sq += __shfl_xor(sq, k); }
    float mu = sm * (1.f / 128.f);
    float var = sq * (1.f / 128.f) - mu * mu;
    float r = rsqrtf(var + 1e-5f);
    out[base + d0] = (v0 - mu) * r * g[d0] + b[d0];
    out[base + d1] = (v1 - mu) * r * g[d1] + b[d1];
}

// ---------------------------------------------------------------- launch
extern "C" void kernel_launch(void* const* d_in, const int* in_sizes, int n_in,
                              void* d_out, int out_size, void* d_ws, size_t ws_size,
                              hipStream_t stream) {
    const float* x      = (const float*)d_in[0];
    const int*   ei     = (const int*)d_in[1];
    const float* ew     = (const float*)d_in[2];
    const int*   smask  = (const int*)d_in[3];
    const float* inW    = (const float*)d_in[4];
    const float* inb    = (const float*)d_in[5];
    const float* ing    = (const float*)d_in[6];
    const float* inbeta = (const float*)d_in[7];
    const float* gWl    = (const float*)d_in[8];
    const float* gbl    = (const float*)d_in[9];
    const float* gWr    = (const float*)d_in[10];
    const float* gbr    = (const float*)d_in[11];
    const float* gWe    = (const float*)d_in[12];
    const float* gatt   = (const float*)d_in[13];
    const float* gbias  = (const float*)d_in[14];
    const float* blkg   = (const float*)d_in[15];
    const float* blkb   = (const float*)d_in[16];
    const float* ctxW   = (const float*)d_in[17];
    const float* ctxb   = (const float*)d_in[18];
    const float* fing   = (const float*)d_in[19];
    const float* finb   = (const float*)d_in[20];
    float* out = (float*)d_out;

    float* ws = (float*)d_ws;
    size_t o = 0;
    float* h      = ws + o;            o += (size_t)NN * HID;
    float* xl     = ws + o;            o += (size_t)NN * HID;
    float* xr     = ws + o;            o += (size_t)NN * HID;
    float* csr_ea = ws + o;            o += ET;
    float* gm     = ws + o;            o += NSTORE * HID;
    int*   offs   = (int*)(ws + o);    o += NN + 1;
    int*   csrsrc = (int*)(ws + o);    o += ET;
    // zero-init region (single memset)
    float* zbase  = ws + o;
    float* wsum   = ws + o;            o += NN;
    float* ssum   = ws + o;            o += NSTORE * HID;
    int*   cnt    = (int*)(ws + o);    o += NN;
    int*   fill   = (int*)(ws + o);    o += NN;
    int*   scnt   = (int*)(ws + o);    o += 64;
    size_t zbytes = (size_t)(NN + NSTORE * HID + NN + NN + 64) * 4;

    hipMemsetAsync((void*)zbase, 0, zbytes, stream);

    const int EB = (EE + 255) / 256;
    const int NB = (NN + 255) / 256;
    const int WB = NN / 4;              // wave-per-node kernels: 4 waves / block, 50000 % 4 == 0
    dim3 ggrid((NN + 63) / 64, 2);

    k_count<<<EB, 256, 0, stream>>>(ei, ew, cnt, wsum);
    k_scan<<<1, 1024, 0, stream>>>(cnt, offs);
    k_scatter<<<EB, 256, 0, stream>>>(ei, ew, offs, fill, csrsrc, csr_ea);
    k_selfloop<<<NB, 256, 0, stream>>>(offs, cnt, wsum, csrsrc, csr_ea);

    // input projection: GELU(x@inW+inb) then LN
    k_gemm<<<ggrid, 256, 0, stream>>>(x, inW, inb, h, NN, 64, 1);
    k_ln<<<WB, 256, 0, stream>>>(h, ing, inbeta);

    for (int l = 0; l < 3; ++l) {
        const float* Wl = gWl + (size_t)l * HID * HID;
        const float* Wr = gWr + (size_t)l * HID * HID;
        k_gemm<<<ggrid, 256, 0, stream>>>(h, Wl, gbl + l * HID, xl, NN, HID, 0);
        k_gemm<<<ggrid, 256, 0, stream>>>(h, Wr, gbr + l * HID, xr, NN, HID, 0);
        k_attn<<<WB, 256, 0, stream>>>(xl, xr, h, offs, csrsrc, csr_ea,
                                       gWe + l * HID, gatt + l * HID, gbias + l * HID,
                                       blkg + l * HID, blkb + l * HID);
    }

    k_store_sum<<<120, 256, 0, stream>>>(h, smask, ssum, scnt);
    k_gate<<<NSTORE, 128, 0, stream>>>(ssum, scnt, ctxW, ctxb, gm);
    k_final<<<WB, 256, 0, stream>>>(h, smask, gm, fing, finb, out);
}

// Round 2
// 886.097 us; speedup vs baseline: 1.0934x; 1.0934x over previous
//
#include <hip/hip_runtime.h>
#include <math.h>

#define NN 50000
#define EE 800000
#define ET (EE + NN)
#define HID 128
#define NSTORE 50

typedef unsigned short ushort_t;
typedef __attribute__((ext_vector_type(8))) short bf8;
typedef __attribute__((ext_vector_type(4))) float f4;

__device__ __forceinline__ float b2f(ushort_t u) {
    union { unsigned int i; float f; } v; v.i = ((unsigned int)u) << 16; return v.f;
}
__device__ __forceinline__ ushort_t f2b(float f) {
    union { float f; unsigned int i; } v; v.f = f;
    unsigned int r = (v.i + 0x7fffu + ((v.i >> 16) & 1u)) >> 16;
    return (ushort_t)r;
}

// ---------------------------------------------------------------- CSR build
__global__ void k_count(const int* __restrict__ ei, const float* __restrict__ ew,
                        int* __restrict__ cnt, float* __restrict__ wsum) {
    int i = blockIdx.x * 256 + threadIdx.x;
    if (i >= EE) return;
    int dst = ei[EE + i];
    atomicAdd(&cnt[dst], 1);
    atomicAdd(&wsum[dst], ew[i]);
}

__global__ __launch_bounds__(1024) void k_scan(const int* __restrict__ cnt, int* __restrict__ offs) {
    __shared__ int part[1024];
    int t = threadIdx.x;
    const int C = (NN + 1023) / 1024;
    int lo = t * C, hi = min(NN, lo + C);
    int s = 0;
    for (int i = lo; i < hi; ++i) s += cnt[i] + 1;   // +1 for self loop
    part[t] = s;
    __syncthreads();
    for (int d = 1; d < 1024; d <<= 1) {
        int v = (t >= d) ? part[t - d] : 0;
        __syncthreads();
        part[t] += v;
        __syncthreads();
    }
    int base = (t == 0) ? 0 : part[t - 1];
    for (int i = lo; i < hi; ++i) { offs[i] = base; base += cnt[i] + 1; }
    if (t == 1023) offs[NN] = part[1023];
}

__global__ void k_scatter(const int* __restrict__ ei, const float* __restrict__ ew,
                          const int* __restrict__ offs, int* __restrict__ fill,
                          int* __restrict__ csr_src, float* __restrict__ csr_ea) {
    int i = blockIdx.x * 256 + threadIdx.x;
    if (i >= EE) return;
    int src = ei[i], dst = ei[EE + i];
    int pos = offs[dst] + atomicAdd(&fill[dst], 1);
    csr_src[pos] = src;
    csr_ea[pos] = ew[i];
}

__global__ void k_selfloop(const int* __restrict__ offs, const int* __restrict__ cnt,
                           const float* __restrict__ wsum,
                           int* __restrict__ csr_src, float* __restrict__ csr_ea) {
    int i = blockIdx.x * 256 + threadIdx.x;
    if (i >= NN) return;
    int pos = offs[i + 1] - 1;                        // last slot of segment
    csr_src[pos] = i;
    csr_ea[pos] = wsum[i] / fmaxf((float)cnt[i], 1.0f);
}

// ---------------------------------------------------------------- dtype conversion
__global__ void k_cvt_x(const float* __restrict__ x, ushort_t* __restrict__ xb) {
    int i = blockIdx.x * 256 + threadIdx.x;
    if (i < NN * 64) xb[i] = f2b(x[i]);
}

// Transposed bf16 weights: Wt[n][k] = W[k][n]
__global__ void k_cvt_w(const float* __restrict__ inW, const float* __restrict__ gWl,
                        const float* __restrict__ gWr,
                        ushort_t* __restrict__ inWt, ushort_t* __restrict__ Wlt,
                        ushort_t* __restrict__ Wrt) {
    int i = blockIdx.x * 256 + threadIdx.x;
    if (i < 128 * 64) {               // inWt[c*64+k] = inW[k*128+c]
        int c = i >> 6, k = i & 63;
        inWt[i] = f2b(inW[k * 128 + c]);
    }
    if (i < 3 * 128 * 128) {          // Wlt[l][n*128+k] = W[l][k*128+n]
        int l = i >> 14, r = i & 16383, nn2 = r >> 7, k = r & 127;
        Wlt[i] = f2b(gWl[(size_t)l * 16384 + k * 128 + nn2]);
        Wrt[i] = f2b(gWr[(size_t)l * 16384 + k * 128 + nn2]);
    }
}

// ---------------------------------------------------------------- bf16 MFMA GEMM (K=128), bf16 out
// out[n][128] = A[n][128] @ Wt^T + bias.  A row-major bf16, Wt[n][k] bf16.
// Block: 256 thr = 4 waves in 2x2 over a 128x128 tile; wave does 4x4 of 16x16x32 MFMAs.
__global__ __launch_bounds__(256) void k_gemm_mfma(const ushort_t* __restrict__ A,
                                                   const ushort_t* __restrict__ Wt,
                                                   const float* __restrict__ bias,
                                                   ushort_t* __restrict__ outb, int n) {
    const int K = 128;
    int lane = threadIdx.x & 63, w = threadIdx.x >> 6;
    int rw = w >> 1, cw = w & 1;
    int q = lane >> 4, l16 = lane & 15;
    int row0 = blockIdx.x * 128 + rw * 64;
    int col0 = cw * 64;
    bf8 z; for (int t = 0; t < 8; ++t) z[t] = 0;

    bf8 bfr[4][4];
#pragma unroll
    for (int kk = 0; kk < 4; ++kk)
#pragma unroll
        for (int j = 0; j < 4; ++j)
            bfr[kk][j] = *(const bf8*)(Wt + (size_t)(col0 + j * 16 + l16) * K + kk * 32 + q * 8);

    f4 acc[4][4];
#pragma unroll
    for (int i = 0; i < 4; ++i)
#pragma unroll
        for (int j = 0; j < 4; ++j) acc[i][j] = (f4)(0.f);

#pragma unroll
    for (int kk = 0; kk < 4; ++kk) {
        bf8 af[4];
#pragma unroll
        for (int i = 0; i < 4; ++i) {
            int r = row0 + i * 16 + l16;
            af[i] = (r < n) ? *(const bf8*)(A + (size_t)r * K + kk * 32 + q * 8) : z;
        }
#pragma unroll
        for (int i = 0; i < 4; ++i)
#pragma unroll
            for (int j = 0; j < 4; ++j)
                acc[i][j] = __builtin_amdgcn_mfma_f32_16x16x32_bf16(af[i], bfr[kk][j], acc[i][j], 0, 0, 0);
    }
#pragma unroll
    for (int i = 0; i < 4; ++i) {
        int gr0 = row0 + i * 16 + q * 4;
#pragma unroll
        for (int j = 0; j < 4; ++j) {
            int gc = col0 + j * 16 + l16;
            float bv = bias[gc];
#pragma unroll
            for (int r = 0; r < 4; ++r) {
                int gr = gr0 + r;
                if (gr < n) outb[(size_t)gr * HID + gc] = f2b(acc[i][j][r] + bv);
            }
        }
    }
}

// ---------------------------------------------------------------- input proj: GELU + LN fused, K=64
__global__ __launch_bounds__(256) void k_inproj(const ushort_t* __restrict__ A,
                                                const ushort_t* __restrict__ Wt,
                                                const float* __restrict__ bias,
                                                const float* __restrict__ g,
                                                const float* __restrict__ be,
                                                float* __restrict__ h,
                                                ushort_t* __restrict__ hb, int n) {
    const int K = 64;
    __shared__ float s1[2][128], s2[2][128];
    int lane = threadIdx.x & 63, w = threadIdx.x >> 6;
    int rw = w >> 1, cw = w & 1;
    int q = lane >> 4, l16 = lane & 15;
    int row0 = blockIdx.x * 128 + rw * 64;
    int col0 = cw * 64;
    bf8 z; for (int t = 0; t < 8; ++t) z[t] = 0;

    bf8 bfr[2][4];
#pragma unroll
    for (int kk = 0; kk < 2; ++kk)
#pragma unroll
        for (int j = 0; j < 4; ++j)
            bfr[kk][j] = *(const bf8*)(Wt + (size_t)(col0 + j * 16 + l16) * K + kk * 32 + q * 8);

    f4 acc[4][4];
#pragma unroll
    for (int i = 0; i < 4; ++i)
#pragma unroll
        for (int j = 0; j < 4; ++j) acc[i][j] = (f4)(0.f);

#pragma unroll
    for (int kk = 0; kk < 2; ++kk) {
        bf8 af[4];
#pragma unroll
        for (int i = 0; i < 4; ++i) {
            int r = row0 + i * 16 + l16;
            af[i] = (r < n) ? *(const bf8*)(A + (size_t)r * K + kk * 32 + q * 8) : z;
        }
#pragma unroll
        for (int i = 0; i < 4; ++i)
#pragma unroll
            for (int j = 0; j < 4; ++j)
                acc[i][j] = __builtin_amdgcn_mfma_f32_16x16x32_bf16(af[i], bfr[kk][j], acc[i][j], 0, 0, 0);
    }
    // bias + exact GELU in place, then per-row partial sums
#pragma unroll
    for (int i = 0; i < 4; ++i) {
#pragma unroll
        for (int j = 0; j < 4; ++j) {
            float bv = bias[col0 + j * 16 + l16];
#pragma unroll
            for (int r = 0; r < 4; ++r) {
                float v = acc[i][j][r] + bv;
                v = 0.5f * v * (1.f + erff(v * 0.70710678118654752f));
                acc[i][j][r] = v;
            }
        }
    }
#pragma unroll
    for (int i = 0; i < 4; ++i) {
#pragma unroll
        for (int r = 0; r < 4; ++r) {
            float sm = acc[i][0][r] + acc[i][1][r] + acc[i][2][r] + acc[i][3][r];
            float sq = acc[i][0][r] * acc[i][0][r] + acc[i][1][r] * acc[i][1][r]
                     + acc[i][2][r] * acc[i][2][r] + acc[i][3][r] * acc[i][3][r];
#pragma unroll
            for (int k = 1; k < 16; k <<= 1) { sm += __shfl_xor(sm, k); sq += __shfl_xor(sq, k); }
            if (l16 == 0) {
                int rl = rw * 64 + i * 16 + q * 4 + r;
                s1[cw][rl] = sm; s2[cw][rl] = sq;
            }
        }
    }
    __syncthreads();
#pragma unroll
    for (int i = 0; i < 4; ++i) {
#pragma unroll
        for (int r = 0; r < 4; ++r) {
            int rl = rw * 64 + i * 16 + q * 4 + r;
            int gr = blockIdx.x * 128 + rl;
            if (gr >= n) continue;
            float sm = s1[0][rl] + s1[1][rl];
            float sq = s2[0][rl] + s2[1][rl];
            float mu = sm * (1.f / 128.f);
            float var = sq * (1.f / 128.f) - mu * mu;
            float rinv = rsqrtf(var + 1e-5f);
#pragma unroll
            for (int j = 0; j < 4; ++j) {
                int gc = col0 + j * 16 + l16;
                float v = (acc[i][j][r] - mu) * rinv * g[gc] + be[gc];
                h[(size_t)gr * HID + gc] = v;
                hb[(size_t)gr * HID + gc] = f2b(v);
            }
        }
    }
}

// ---------------------------------------------------------------- GATv2 attention, wave per dst node
// bf16 xl/xr gathers; fused +bias +residual +LayerNorm; writes h (f32) and hb (bf16)
__global__ __launch_bounds__(256) void k_attn(const ushort_t* __restrict__ xl,
                                              const ushort_t* __restrict__ xr,
                                              float* __restrict__ h,
                                              ushort_t* __restrict__ hb,
                                              const int* __restrict__ offs,
                                              const int* __restrict__ csr_src,
                                              const float* __restrict__ csr_ea,
                                              const float* __restrict__ We,
                                              const float* __restrict__ att,
                                              const float* __restrict__ gbias,
                                              const float* __restrict__ g,
                                              const float* __restrict__ b) {
    int wid = (blockIdx.x * 256 + threadIdx.x) >> 6;
    int lane = threadIdx.x & 63;
    if (wid >= NN) return;
    int d0 = lane * 2, d1 = d0 + 1;
    size_t base = (size_t)wid * HID;
    ushort2 xru = *(const ushort2*)(xr + base + d0);
    float xr0 = b2f(xru.x), xr1 = b2f(xru.y);
    float a0 = att[d0], a1 = att[d1];
    float w0 = We[d0], w1 = We[d1];
    int p0 = offs[wid], p1 = offs[wid + 1];
    float m = -3.0e38f, Z = 0.f, acc0 = 0.f, acc1 = 0.f;
    for (int p = p0; p < p1; ++p) {
        int src = csr_src[p];
        float ea = csr_ea[p];
        ushort2 xu = *(const ushort2*)(xl + (size_t)src * HID + d0);
        float xl0 = b2f(xu.x), xl1 = b2f(xu.y);
        float t0 = xl0 + xr0 + ea * w0;
        float t1 = xl1 + xr1 + ea * w1;
        t0 = (t0 > 0.f) ? t0 : 0.2f * t0;     // leaky_relu 0.2
        t1 = (t1 > 0.f) ? t1 : 0.2f * t1;
        float part = a0 * t0 + a1 * t1;
        part += __shfl_xor(part, 1);          // reduce 4 lanes of head
        part += __shfl_xor(part, 2);
        float nm = fmaxf(m, part);
        float s = __expf(m - nm);
        float wgt = __expf(part - nm);
        Z = Z * s + wgt;
        acc0 = acc0 * s + wgt * xl0;
        acc1 = acc1 * s + wgt * xl1;
        m = nm;
    }
    float inv = 1.f / (Z + 1e-16f);
    float2 hv = *(const float2*)(h + base + d0);
    float o0 = acc0 * inv + gbias[d0] + hv.x;
    float o1 = acc1 * inv + gbias[d1] + hv.y;
    float sm = o0 + o1, sq = o0 * o0 + o1 * o1;
#pragma unroll
    for (int k = 1; k < 64; k <<= 1) { sm += __shfl_xor(sm, k); sq += __shfl_xor(sq, k); }
    float mu = sm * (1.f / 128.f);
    float var = sq * (1.f / 128.f) - mu * mu;
    float r = rsqrtf(var + 1e-5f);
    float v0 = (o0 - mu) * r * g[d0] + b[d0];
    float v1 = (o1 - mu) * r * g[d1] + b[d1];
    *(float2*)(h + base + d0) = make_float2(v0, v1);
    ushort2 hu; hu.x = f2b(v0); hu.y = f2b(v1);
    *(ushort2*)(hb + base + d0) = hu;
}

// ---------------------------------------------------------------- per-store segment sum
__global__ __launch_bounds__(256) void k_store_sum(const float* __restrict__ h,
                                                   const int* __restrict__ mask,
                                                   float* __restrict__ ssum,
                                                   int* __restrict__ scnt) {
    __shared__ float ls[NSTORE * HID];
    __shared__ int lc[NSTORE];
    int t = threadIdx.x;
    for (int i = t; i < NSTORE * HID; i += 256) ls[i] = 0.f;
    if (t < NSTORE) lc[t] = 0;
    __syncthreads();
    int wid = blockIdx.x * 4 + (t >> 6);
    int lane = t & 63;
    int nw = gridDim.x * 4;
    int d0 = lane * 2, d1 = d0 + 1;
    for (int node = wid; node < NN; node += nw) {
        int s = mask[node];
        size_t base = (size_t)node * HID;
        atomicAdd(&ls[s * HID + d0], h[base + d0]);
        atomicAdd(&ls[s * HID + d1], h[base + d1]);
        if (lane == 0) atomicAdd(&lc[s], 1);
    }
    __syncthreads();
    for (int i = t; i < NSTORE * HID; i += 256) atomicAdd(&ssum[i], ls[i]);
    if (t < NSTORE) atomicAdd(&scnt[t], lc[t]);
}

// ---------------------------------------------------------------- gate
__global__ __launch_bounds__(128) void k_gate(const float* __restrict__ ssum,
                                              const int* __restrict__ scnt,
                                              const float* __restrict__ ctxW,
                                              const float* __restrict__ ctxb,
                                              float* __restrict__ gm) {
    __shared__ float mloc[HID];
    int s = blockIdx.x, t = threadIdx.x;
    float c = fmaxf((float)scnt[s], 1.f);
    float mk = ssum[s * HID + t] / c;
    mloc[t] = mk;
    __syncthreads();
    float acc = ctxb[t];
    for (int j = 0; j < HID; ++j) acc += mloc[j] * ctxW[j * HID + t];
    float gate = 1.f / (1.f + __expf(-acc));
    gm[s * HID + t] = gate * mk;
}

// ---------------------------------------------------------------- final: out = LN(h + gm[store])
__global__ __launch_bounds__(256) void k_final(const float* __restrict__ h,
                                               const int* __restrict__ mask,
                                               const float* __restrict__ gm,
                                               const float* __restrict__ g,
                                               const float* __restrict__ b,
                                               float* __restrict__ out) {
    int wid = (blockIdx.x * 256 + threadIdx.x) >> 6;
    int lane = threadIdx.x & 63;
    if (wid >= NN) return;
    size_t base = (size_t)wid * HID;
    int s = mask[wid];
    int d0 = lane * 2, d1 = d0 + 1;
    float v0 = h[base + d0] + gm[s * HID + d0];
    float v1 = h[base + d1] + gm[s * HID + d1];
    float sm = v0 + v1, sq = v0 * v0 + v1 * v1;
#pragma unroll
    for (int k = 1; k < 64; k <<= 1) { sm += __shfl_xor(sm, k); sq += __shfl_xor(sq, k); }
    float mu = sm * (1.f / 128.f);
    float var = sq * (1.f / 128.f) - mu * mu;
    float r = rsqrtf(var + 1e-5f);
    out[base + d0] = (v0 - mu) * r * g[d0] + b[d0];
    out[base + d1] = (v1 - mu) * r * g[d1] + b[d1];
}

// ---------------------------------------------------------------- launch
extern "C" void kernel_launch(void* const* d_in, const int* in_sizes, int n_in,
                              void* d_out, int out_size, void* d_ws, size_t ws_size,
                              hipStream_t stream) {
    const float* x      = (const float*)d_in[0];
    const int*   ei     = (const int*)d_in[1];
    const float* ew     = (const float*)d_in[2];
    const int*   smask  = (const int*)d_in[3];
    const float* inW    = (const float*)d_in[4];
    const float* inb    = (const float*)d_in[5];
    const float* ing    = (const float*)d_in[6];
    const float* inbeta = (const float*)d_in[7];
    const float* gWl    = (const float*)d_in[8];
    const float* gbl    = (const float*)d_in[9];
    const float* gWr    = (const float*)d_in[10];
    const float* gbr    = (const float*)d_in[11];
    const float* gWe    = (const float*)d_in[12];
    const float* gatt   = (const float*)d_in[13];
    const float* gbias  = (const float*)d_in[14];
    const float* blkg   = (const float*)d_in[15];
    const float* blkb   = (const float*)d_in[16];
    const float* ctxW   = (const float*)d_in[17];
    const float* ctxb   = (const float*)d_in[18];
    const float* fing   = (const float*)d_in[19];
    const float* finb   = (const float*)d_in[20];
    float* out = (float*)d_out;

    float* ws = (float*)d_ws;
    size_t o = 0;
    float*    h      = ws + o;              o += (size_t)NN * HID;       // 6.4M
    float*    csr_ea = ws + o;              o += ET;                     // 850000
    float*    gm     = ws + o;              o += NSTORE * HID;           // 6400
    int*      offs   = (int*)(ws + o);      o += 50004;                  // NN+1 padded
    int*      csrsrc = (int*)(ws + o);      o += ET;
    ushort_t* xb     = (ushort_t*)(ws + o); o += (size_t)NN * 64 / 2;    // bf16 x
    ushort_t* hb     = (ushort_t*)(ws + o); o += (size_t)NN * HID / 2;   // bf16 h
    ushort_t* xlb    = (ushort_t*)(ws + o); o += (size_t)NN * HID / 2;
    ushort_t* xrb    = (ushort_t*)(ws + o); o += (size_t)NN * HID / 2;
    ushort_t* inWt   = (ushort_t*)(ws + o); o += 128 * 64 / 2;
    ushort_t* Wlt    = (ushort_t*)(ws + o); o += 3 * 128 * 128 / 2;
    ushort_t* Wrt    = (ushort_t*)(ws + o); o += 3 * 128 * 128 / 2;
    // zero-init region (single memset)
    float*    zbase  = ws + o;
    float*    wsum   = ws + o;              o += NN;
    float*    ssum   = ws + o;              o += NSTORE * HID;
    int*      cnt    = (int*)(ws + o);      o += NN;
    int*      fill   = (int*)(ws + o);      o += NN;
    int*      scnt   = (int*)(ws + o);      o += 64;
    size_t zbytes = (size_t)(NN + NSTORE * HID + NN + NN + 64) * 4;

    hipMemsetAsync((void*)zbase, 0, zbytes, stream);

    const int EB = (EE + 255) / 256;
    const int NB = (NN + 255) / 256;
    const int WB = NN / 4;                    // wave-per-node kernels
    const int GB = (NN + 127) / 128;          // 128-row GEMM tiles

    k_cvt_x<<<(NN * 64 + 255) / 256, 256, 0, stream>>>(x, xb);
    k_cvt_w<<<(3 * 128 * 128 + 255) / 256, 256, 0, stream>>>(inW, gWl, gWr, inWt, Wlt, Wrt);

    k_count<<<EB, 256, 0, stream>>>(ei, ew, cnt, wsum);
    k_scan<<<1, 1024, 0, stream>>>(cnt, offs);
    k_scatter<<<EB, 256, 0, stream>>>(ei, ew, offs, fill, csrsrc, csr_ea);
    k_selfloop<<<NB, 256, 0, stream>>>(offs, cnt, wsum, csrsrc, csr_ea);

    // input projection: GELU(x@inW+inb) then LN, fused
    k_inproj<<<GB, 256, 0, stream>>>(xb, inWt, inb, ing, inbeta, h, hb, NN);

    for (int l = 0; l < 3; ++l) {
        k_gemm_mfma<<<GB, 256, 0, stream>>>(hb, Wlt + (size_t)l * HID * HID, gbl + l * HID, xlb, NN);
        k_gemm_mfma<<<GB, 256, 0, stream>>>(hb, Wrt + (size_t)l * HID * HID, gbr + l * HID, xrb, NN);
        k_attn<<<WB, 256, 0, stream>>>(xlb, xrb, h, hb, offs, csrsrc, csr_ea,
                                       gWe + l * HID, gatt + l * HID, gbias + l * HID,
                                       blkg + l * HID, blkb + l * HID);
    }

    k_store_sum<<<120, 256, 0, stream>>>(h, smask, ssum, scnt);
    k_gate<<<NSTORE, 128, 0, stream>>>(ssum, scnt, ctxW, ctxb, gm);
    k_final<<<WB, 256, 0, stream>>>(h, smask, gm, fing, finb, out);
}

// Round 3
// 633.156 us; speedup vs baseline: 1.5303x; 1.3995x over previous
//
#include <hip/hip_runtime.h>
#include <math.h>

#define NN 50000
#define EE 800000
#define ET (EE + NN)
#define HID 128
#define NSTORE 50
#define NBL 196                      // ceil(NN/256)

typedef unsigned short ushort_t;
typedef __attribute__((ext_vector_type(8))) short bf8;
typedef __attribute__((ext_vector_type(4))) float f4;
typedef __attribute__((ext_vector_type(4))) unsigned int u4;

__device__ __forceinline__ float b2f(ushort_t u) {
    union { unsigned int i; float f; } v; v.i = ((unsigned int)u) << 16; return v.f;
}
__device__ __forceinline__ ushort_t f2b(float f) {
    union { float f; unsigned int i; } v; v.f = f;
    unsigned int r = (v.i + 0x7fffu + ((v.i >> 16) & 1u)) >> 16;
    return (ushort_t)r;
}
__device__ __forceinline__ void b2f2(unsigned int u, float& lo, float& hi) {
    union { unsigned int i; float f; } a, c;
    a.i = u << 16; c.i = u & 0xffff0000u;
    lo = a.f; hi = c.f;
}
__device__ __forceinline__ unsigned int pk2(float lo, float hi) {
    return (unsigned int)f2b(lo) | ((unsigned int)f2b(hi) << 16);
}

// ---------------------------------------------------------------- CSR build
__global__ void k_count(const int* __restrict__ ei, const float* __restrict__ ew,
                        int* __restrict__ cnt, float* __restrict__ wsum) {
    int i = blockIdx.x * 256 + threadIdx.x;
    if (i >= EE) return;
    int dst = ei[EE + i];
    atomicAdd(&cnt[dst], 1);
    atomicAdd(&wsum[dst], ew[i]);
}

// per-256-chunk sums of (cnt+1)
__global__ __launch_bounds__(256) void k_psum(const int* __restrict__ cnt, int* __restrict__ bsum) {
    int t = threadIdx.x, bidx = blockIdx.x;
    int i = bidx * 256 + t;
    int v = (i < NN) ? cnt[i] + 1 : 0;
#pragma unroll
    for (int d = 1; d < 64; d <<= 1) v += __shfl_xor(v, d);
    __shared__ int ws4[4];
    if ((t & 63) == 0) ws4[t >> 6] = v;
    __syncthreads();
    if (t == 0) bsum[bidx] = ws4[0] + ws4[1] + ws4[2] + ws4[3];
}

// scan the 196 block sums (single small block)
__global__ __launch_bounds__(256) void k_scanb(const int* __restrict__ bsum,
                                               int* __restrict__ bbase, int* __restrict__ offs) {
    __shared__ int s[256];
    int t = threadIdx.x;
    int v = (t < NBL) ? bsum[t] : 0;
    s[t] = v;
    __syncthreads();
    for (int d = 1; d < 256; d <<= 1) {
        int u = (t >= d) ? s[t - d] : 0;
        __syncthreads();
        s[t] += u;
        __syncthreads();
    }
    if (t < NBL) bbase[t] = s[t] - v;    // exclusive base
    if (t == 0) offs[NN] = ET;
}

// per-chunk exclusive prefix -> offs
__global__ __launch_bounds__(256) void k_offs(const int* __restrict__ cnt,
                                              const int* __restrict__ bbase, int* __restrict__ offs) {
    __shared__ int wsum4[4];
    int t = threadIdx.x, bidx = blockIdx.x;
    int i = bidx * 256 + t;
    int v = (i < NN) ? cnt[i] + 1 : 0;
    int lane = t & 63, w = t >> 6;
    int sc = v;
#pragma unroll
    for (int d = 1; d < 64; d <<= 1) {
        int u = __shfl_up(sc, d);
        if (lane >= d) sc += u;
    }
    if (lane == 63) wsum4[w] = sc;
    __syncthreads();
    int wo = 0;
    for (int k = 0; k < w; ++k) wo += wsum4[k];
    if (i < NN) offs[i] = bbase[bidx] + wo + sc - v;
}

// scatter edges + append self loops (fused)
__global__ void k_scatter(const int* __restrict__ ei, const float* __restrict__ ew,
                          const int* __restrict__ offs, const int* __restrict__ cnt,
                          const float* __restrict__ wsum, int* __restrict__ fill,
                          int* __restrict__ csr_src, float* __restrict__ csr_ea) {
    int i = blockIdx.x * 256 + threadIdx.x;
    if (i < EE) {
        int src = ei[i], dst = ei[EE + i];
        int pos = offs[dst] + atomicAdd(&fill[dst], 1);
        csr_src[pos] = src;
        csr_ea[pos] = ew[i];
    } else if (i < ET) {
        int nd = i - EE;
        int pos = offs[nd + 1] - 1;                  // last slot of segment
        csr_src[pos] = nd;
        csr_ea[pos] = wsum[nd] / fmaxf((float)cnt[nd], 1.0f);
    }
}

// ---------------------------------------------------------------- dtype conversion (merged)
__global__ void k_cvt(const float* __restrict__ x, const float* __restrict__ inW,
                      const float* __restrict__ gWl, const float* __restrict__ gWr,
                      ushort_t* __restrict__ xb, ushort_t* __restrict__ inWt,
                      ushort_t* __restrict__ Wlt, ushort_t* __restrict__ Wrt) {
    int i = blockIdx.x * 256 + threadIdx.x;
    if (i < NN * 64) xb[i] = f2b(x[i]);
    if (i < 128 * 64) {               // inWt[c*64+k] = inW[k*128+c]
        int c = i >> 6, k = i & 63;
        inWt[i] = f2b(inW[k * 128 + c]);
    }
    if (i < 3 * 128 * 128) {          // Wlt[l][n*128+k] = W[l][k*128+n]
        int l = i >> 14, r = i & 16383, nn2 = r >> 7, k = r & 127;
        Wlt[i] = f2b(gWl[(size_t)l * 16384 + k * 128 + nn2]);
        Wrt[i] = f2b(gWr[(size_t)l * 16384 + k * 128 + nn2]);
    }
}

// ---------------------------------------------------------------- bf16 MFMA dual GEMM (K=128)
// y=0: xlb = hb@Wl^T+bl ; y=1: xrb = hb@Wr^T+br
__global__ __launch_bounds__(256) void k_gemm2(const ushort_t* __restrict__ A,
                                               const ushort_t* __restrict__ Wt0,
                                               const ushort_t* __restrict__ Wt1,
                                               const float* __restrict__ b0,
                                               const float* __restrict__ b1,
                                               ushort_t* __restrict__ o0,
                                               ushort_t* __restrict__ o1, int n) {
    const int K = 128;
    const ushort_t* Wt = blockIdx.y ? Wt1 : Wt0;
    const float* bias = blockIdx.y ? b1 : b0;
    ushort_t* outb = blockIdx.y ? o1 : o0;
    int lane = threadIdx.x & 63, w = threadIdx.x >> 6;
    int rw = w >> 1, cw = w & 1;
    int q = lane >> 4, l16 = lane & 15;
    int row0 = blockIdx.x * 128 + rw * 64;
    int col0 = cw * 64;
    bf8 z; for (int t = 0; t < 8; ++t) z[t] = 0;

    bf8 bfr[4][4];
#pragma unroll
    for (int kk = 0; kk < 4; ++kk)
#pragma unroll
        for (int j = 0; j < 4; ++j)
            bfr[kk][j] = *(const bf8*)(Wt + (size_t)(col0 + j * 16 + l16) * K + kk * 32 + q * 8);

    f4 acc[4][4];
#pragma unroll
    for (int i = 0; i < 4; ++i)
#pragma unroll
        for (int j = 0; j < 4; ++j) acc[i][j] = (f4)(0.f);

#pragma unroll
    for (int kk = 0; kk < 4; ++kk) {
        bf8 af[4];
#pragma unroll
        for (int i = 0; i < 4; ++i) {
            int r = row0 + i * 16 + l16;
            af[i] = (r < n) ? *(const bf8*)(A + (size_t)r * K + kk * 32 + q * 8) : z;
        }
#pragma unroll
        for (int i = 0; i < 4; ++i)
#pragma unroll
            for (int j = 0; j < 4; ++j)
                acc[i][j] = __builtin_amdgcn_mfma_f32_16x16x32_bf16(af[i], bfr[kk][j], acc[i][j], 0, 0, 0);
    }
#pragma unroll
    for (int i = 0; i < 4; ++i) {
        int gr0 = row0 + i * 16 + q * 4;
#pragma unroll
        for (int j = 0; j < 4; ++j) {
            int gc = col0 + j * 16 + l16;
            float bv = bias[gc];
#pragma unroll
            for (int r = 0; r < 4; ++r) {
                int gr = gr0 + r;
                if (gr < n) outb[(size_t)gr * HID + gc] = f2b(acc[i][j][r] + bv);
            }
        }
    }
}

// ---------------------------------------------------------------- input proj: GELU + LN fused, K=64
__global__ __launch_bounds__(256) void k_inproj(const ushort_t* __restrict__ A,
                                                const ushort_t* __restrict__ Wt,
                                                const float* __restrict__ bias,
                                                const float* __restrict__ g,
                                                const float* __restrict__ be,
                                                float* __restrict__ h,
                                                ushort_t* __restrict__ hb, int n) {
    const int K = 64;
    __shared__ float s1[2][128], s2[2][128];
    int lane = threadIdx.x & 63, w = threadIdx.x >> 6;
    int rw = w >> 1, cw = w & 1;
    int q = lane >> 4, l16 = lane & 15;
    int row0 = blockIdx.x * 128 + rw * 64;
    int col0 = cw * 64;
    bf8 z; for (int t = 0; t < 8; ++t) z[t] = 0;

    bf8 bfr[2][4];
#pragma unroll
    for (int kk = 0; kk < 2; ++kk)
#pragma unroll
        for (int j = 0; j < 4; ++j)
            bfr[kk][j] = *(const bf8*)(Wt + (size_t)(col0 + j * 16 + l16) * K + kk * 32 + q * 8);

    f4 acc[4][4];
#pragma unroll
    for (int i = 0; i < 4; ++i)
#pragma unroll
        for (int j = 0; j < 4; ++j) acc[i][j] = (f4)(0.f);

#pragma unroll
    for (int kk = 0; kk < 2; ++kk) {
        bf8 af[4];
#pragma unroll
        for (int i = 0; i < 4; ++i) {
            int r = row0 + i * 16 + l16;
            af[i] = (r < n) ? *(const bf8*)(A + (size_t)r * K + kk * 32 + q * 8) : z;
        }
#pragma unroll
        for (int i = 0; i < 4; ++i)
#pragma unroll
            for (int j = 0; j < 4; ++j)
                acc[i][j] = __builtin_amdgcn_mfma_f32_16x16x32_bf16(af[i], bfr[kk][j], acc[i][j], 0, 0, 0);
    }
#pragma unroll
    for (int i = 0; i < 4; ++i) {
#pragma unroll
        for (int j = 0; j < 4; ++j) {
            float bv = bias[col0 + j * 16 + l16];
#pragma unroll
            for (int r = 0; r < 4; ++r) {
                float v = acc[i][j][r] + bv;
                v = 0.5f * v * (1.f + erff(v * 0.70710678118654752f));
                acc[i][j][r] = v;
            }
        }
    }
#pragma unroll
    for (int i = 0; i < 4; ++i) {
#pragma unroll
        for (int r = 0; r < 4; ++r) {
            float sm = acc[i][0][r] + acc[i][1][r] + acc[i][2][r] + acc[i][3][r];
            float sq = acc[i][0][r] * acc[i][0][r] + acc[i][1][r] * acc[i][1][r]
                     + acc[i][2][r] * acc[i][2][r] + acc[i][3][r] * acc[i][3][r];
#pragma unroll
            for (int k = 1; k < 16; k <<= 1) { sm += __shfl_xor(sm, k); sq += __shfl_xor(sq, k); }
            if (l16 == 0) {
                int rl = rw * 64 + i * 16 + q * 4 + r;
                s1[cw][rl] = sm; s2[cw][rl] = sq;
            }
        }
    }
    __syncthreads();
#pragma unroll
    for (int i = 0; i < 4; ++i) {
#pragma unroll
        for (int r = 0; r < 4; ++r) {
            int rl = rw * 64 + i * 16 + q * 4 + r;
            int gr = blockIdx.x * 128 + rl;
            if (gr >= n) continue;
            float sm = s1[0][rl] + s1[1][rl];
            float sq = s2[0][rl] + s2[1][rl];
            float mu = sm * (1.f / 128.f);
            float var = sq * (1.f / 128.f) - mu * mu;
            float rinv = rsqrtf(var + 1e-5f);
#pragma unroll
            for (int j = 0; j < 4; ++j) {
                int gc = col0 + j * 16 + l16;
                float v = (acc[i][j][r] - mu) * rinv * g[gc] + be[gc];
                h[(size_t)gr * HID + gc] = v;
                hb[(size_t)gr * HID + gc] = f2b(v);
            }
        }
    }
}

// ---------------------------------------------------------------- GATv2 attention
// wave per dst node; 16 lanes = one edge (lane = head, DH=8 in-lane); 4 edges/step.
// No online max: logits are O(10), exp() safe in fp32; softmax ratio unchanged.
__global__ __launch_bounds__(256) void k_attn(const ushort_t* __restrict__ xl,
                                              const ushort_t* __restrict__ xr,
                                              float* __restrict__ h,
                                              ushort_t* __restrict__ hb,
                                              const int* __restrict__ offs,
                                              const int* __restrict__ csr_src,
                                              const float* __restrict__ csr_ea,
                                              const float* __restrict__ We,
                                              const float* __restrict__ att,
                                              const float* __restrict__ gbias,
                                              const float* __restrict__ g,
                                              const float* __restrict__ b) {
    int wid = (blockIdx.x * 256 + threadIdx.x) >> 6;
    int lane = threadIdx.x & 63;
    if (wid >= NN) return;
    int hd = lane & 15;          // head index (16 heads; DH=8 in-lane)
    int grp = lane >> 4;         // edge subgroup 0..3
    int dbase = hd * 8;
    size_t base = (size_t)wid * HID;

    float xr8[8], at8[8], we8[8];
    {
        u4 uxr = *(const u4*)(xr + base + dbase);
        b2f2(uxr.x, xr8[0], xr8[1]); b2f2(uxr.y, xr8[2], xr8[3]);
        b2f2(uxr.z, xr8[4], xr8[5]); b2f2(uxr.w, xr8[6], xr8[7]);
        f4 a0 = *(const f4*)(att + dbase), a1 = *(const f4*)(att + dbase + 4);
        at8[0] = a0.x; at8[1] = a0.y; at8[2] = a0.z; at8[3] = a0.w;
        at8[4] = a1.x; at8[5] = a1.y; at8[6] = a1.z; at8[7] = a1.w;
        f4 w0 = *(const f4*)(We + dbase), w1 = *(const f4*)(We + dbase + 4);
        we8[0] = w0.x; we8[1] = w0.y; we8[2] = w0.z; we8[3] = w0.w;
        we8[4] = w1.x; we8[5] = w1.y; we8[6] = w1.z; we8[7] = w1.w;
    }
    int p0 = offs[wid], p1 = offs[wid + 1];
    float Z = 0.f;
    float acc[8];
#pragma unroll
    for (int q = 0; q < 8; ++q) acc[q] = 0.f;

#define QUAD(EJ, MASKED)                                                        \
    {                                                                           \
        int ei_ = (EJ) + grp;                                                   \
        int s_ = __shfl(sv, ei_);                                               \
        float ea_ = __shfl(evl, ei_);                                           \
        bool val_ = MASKED ? (ei_ < mm) : true;                                 \
        u4 ux_ = *(const u4*)(xl + (size_t)s_ * HID + dbase);                   \
        float x_[8];                                                            \
        b2f2(ux_.x, x_[0], x_[1]); b2f2(ux_.y, x_[2], x_[3]);                   \
        b2f2(ux_.z, x_[4], x_[5]); b2f2(ux_.w, x_[6], x_[7]);                   \
        float lg_ = 0.f;                                                        \
        _Pragma("unroll")                                                       \
        for (int q_ = 0; q_ < 8; ++q_) {                                        \
            float t_ = x_[q_] + xr8[q_] + ea_ * we8[q_];                        \
            t_ = (t_ > 0.f) ? t_ : 0.2f * t_;                                   \
            lg_ = fmaf(at8[q_], t_, lg_);                                       \
        }                                                                       \
        float w_ = val_ ? __expf(lg_) : 0.f;                                    \
        Z += w_;                                                                \
        _Pragma("unroll")                                                       \
        for (int q_ = 0; q_ < 8; ++q_) acc[q_] = fmaf(w_, x_[q_], acc[q_]);     \
    }

    for (int cb = p0; cb < p1; cb += 64) {
        int mm = min(64, p1 - cb);
        int sv = (lane < mm) ? csr_src[cb + lane] : 0;
        float evl = (lane < mm) ? csr_ea[cb + lane] : 0.f;
        int j = 0;
        for (; j + 8 <= mm; j += 8) { QUAD(j, false) QUAD(j + 4, false) }
        for (; j < mm; j += 4) QUAD(j, true)
    }
#undef QUAD

    // combine the 4 edge subgroups
    Z += __shfl_xor(Z, 16); Z += __shfl_xor(Z, 32);
#pragma unroll
    for (int q = 0; q < 8; ++q) {
        acc[q] += __shfl_xor(acc[q], 16);
        acc[q] += __shfl_xor(acc[q], 32);
    }
    float inv = 1.f / (Z + 1e-16f);

    // residual + LN over the 128 dims held by the 16 head-lanes
    f4 hv0 = *(const f4*)(h + base + dbase);
    f4 hv1 = *(const f4*)(h + base + dbase + 4);
    float hres[8] = {hv0.x, hv0.y, hv0.z, hv0.w, hv1.x, hv1.y, hv1.z, hv1.w};
    f4 gb0 = *(const f4*)(gbias + dbase), gb1 = *(const f4*)(gbias + dbase + 4);
    float gb8[8] = {gb0.x, gb0.y, gb0.z, gb0.w, gb1.x, gb1.y, gb1.z, gb1.w};
    float o[8], sm = 0.f, sq = 0.f;
#pragma unroll
    for (int q = 0; q < 8; ++q) {
        o[q] = acc[q] * inv + gb8[q] + hres[q];
        sm += o[q]; sq += o[q] * o[q];
    }
#pragma unroll
    for (int k = 1; k < 16; k <<= 1) { sm += __shfl_xor(sm, k); sq += __shfl_xor(sq, k); }
    float mu = sm * (1.f / 128.f);
    float var = sq * (1.f / 128.f) - mu * mu;
    float rinv = rsqrtf(var + 1e-5f);
    f4 g0 = *(const f4*)(g + dbase), g1 = *(const f4*)(g + dbase + 4);
    float g8[8] = {g0.x, g0.y, g0.z, g0.w, g1.x, g1.y, g1.z, g1.w};
    f4 b0 = *(const f4*)(b + dbase), b1 = *(const f4*)(b + dbase + 4);
    float b8[8] = {b0.x, b0.y, b0.z, b0.w, b1.x, b1.y, b1.z, b1.w};
    float v8[8];
#pragma unroll
    for (int q = 0; q < 8; ++q) v8[q] = (o[q] - mu) * rinv * g8[q] + b8[q];
    if (grp == 0) {
        f4 s0 = {v8[0], v8[1], v8[2], v8[3]};
        f4 s1 = {v8[4], v8[5], v8[6], v8[7]};
        *(f4*)(h + base + dbase) = s0;
        *(f4*)(h + base + dbase + 4) = s1;
        u4 hu;
        hu.x = pk2(v8[0], v8[1]); hu.y = pk2(v8[2], v8[3]);
        hu.z = pk2(v8[4], v8[5]); hu.w = pk2(v8[6], v8[7]);
        *(u4*)(hb + base + dbase) = hu;
    }
}

// ---------------------------------------------------------------- per-store segment sum
__global__ __launch_bounds__(256) void k_store_sum(const float* __restrict__ h,
                                                   const int* __restrict__ mask,
                                                   float* __restrict__ ssum,
                                                   int* __restrict__ scnt) {
    __shared__ float ls[NSTORE * HID];
    __shared__ int lc[NSTORE];
    int t = threadIdx.x;
    for (int i = t; i < NSTORE * HID; i += 256) ls[i] = 0.f;
    if (t < NSTORE) lc[t] = 0;
    __syncthreads();
    int wid = blockIdx.x * 4 + (t >> 6);
    int lane = t & 63;
    int nw = gridDim.x * 4;
    int d0 = lane * 2, d1 = d0 + 1;
    for (int node = wid; node < NN; node += nw) {
        int s = mask[node];
        size_t base = (size_t)node * HID;
        atomicAdd(&ls[s * HID + d0], h[base + d0]);
        atomicAdd(&ls[s * HID + d1], h[base + d1]);
        if (lane == 0) atomicAdd(&lc[s], 1);
    }
    __syncthreads();
    for (int i = t; i < NSTORE * HID; i += 256) atomicAdd(&ssum[i], ls[i]);
    if (t < NSTORE) atomicAdd(&scnt[t], lc[t]);
}

// ---------------------------------------------------------------- gate
__global__ __launch_bounds__(128) void k_gate(const float* __restrict__ ssum,
                                              const int* __restrict__ scnt,
                                              const float* __restrict__ ctxW,
                                              const float* __restrict__ ctxb,
                                              float* __restrict__ gm) {
    __shared__ float mloc[HID];
    int s = blockIdx.x, t = threadIdx.x;
    float c = fmaxf((float)scnt[s], 1.f);
    float mk = ssum[s * HID + t] / c;
    mloc[t] = mk;
    __syncthreads();
    float acc = ctxb[t];
    for (int j = 0; j < HID; ++j) acc += mloc[j] * ctxW[j * HID + t];
    float gate = 1.f / (1.f + __expf(-acc));
    gm[s * HID + t] = gate * mk;
}

// ---------------------------------------------------------------- final: out = LN(h + gm[store])
__global__ __launch_bounds__(256) void k_final(const float* __restrict__ h,
                                               const int* __restrict__ mask,
                                               const float* __restrict__ gm,
                                               const float* __restrict__ g,
                                               const float* __restrict__ b,
                                               float* __restrict__ out) {
    int wid = (blockIdx.x * 256 + threadIdx.x) >> 6;
    int lane = threadIdx.x & 63;
    if (wid >= NN) return;
    size_t base = (size_t)wid * HID;
    int s = mask[wid];
    int d0 = lane * 2, d1 = d0 + 1;
    float v0 = h[base + d0] + gm[s * HID + d0];
    float v1 = h[base + d1] + gm[s * HID + d1];
    float sm = v0 + v1, sq = v0 * v0 + v1 * v1;
#pragma unroll
    for (int k = 1; k < 64; k <<= 1) { sm += __shfl_xor(sm, k); sq += __shfl_xor(sq, k); }
    float mu = sm * (1.f / 128.f);
    float var = sq * (1.f / 128.f) - mu * mu;
    float r = rsqrtf(var + 1e-5f);
    out[base + d0] = (v0 - mu) * r * g[d0] + b[d0];
    out[base + d1] = (v1 - mu) * r * g[d1] + b[d1];
}

// ---------------------------------------------------------------- launch
extern "C" void kernel_launch(void* const* d_in, const int* in_sizes, int n_in,
                              void* d_out, int out_size, void* d_ws, size_t ws_size,
                              hipStream_t stream) {
    const float* x      = (const float*)d_in[0];
    const int*   ei     = (const int*)d_in[1];
    const float* ew     = (const float*)d_in[2];
    const int*   smask  = (const int*)d_in[3];
    const float* inW    = (const float*)d_in[4];
    const float* inb    = (const float*)d_in[5];
    const float* ing    = (const float*)d_in[6];
    const float* inbeta = (const float*)d_in[7];
    const float* gWl    = (const float*)d_in[8];
    const float* gbl    = (const float*)d_in[9];
    const float* gWr    = (const float*)d_in[10];
    const float* gbr    = (const float*)d_in[11];
    const float* gWe    = (const float*)d_in[12];
    const float* gatt   = (const float*)d_in[13];
    const float* gbias  = (const float*)d_in[14];
    const float* blkg   = (const float*)d_in[15];
    const float* blkb   = (const float*)d_in[16];
    const float* ctxW   = (const float*)d_in[17];
    const float* ctxb   = (const float*)d_in[18];
    const float* fing   = (const float*)d_in[19];
    const float* finb   = (const float*)d_in[20];
    float* out = (float*)d_out;

    float* ws = (float*)d_ws;
    size_t o = 0;
    float*    h      = ws + o;              o += (size_t)NN * HID;
    float*    csr_ea = ws + o;              o += ET;
    float*    gm     = ws + o;              o += NSTORE * HID;
    int*      offs   = (int*)(ws + o);      o += 50004;
    int*      csrsrc = (int*)(ws + o);      o += ET;
    ushort_t* xb     = (ushort_t*)(ws + o); o += (size_t)NN * 64 / 2;
    ushort_t* hb     = (ushort_t*)(ws + o); o += (size_t)NN * HID / 2;
    ushort_t* xlb    = (ushort_t*)(ws + o); o += (size_t)NN * HID / 2;
    ushort_t* xrb    = (ushort_t*)(ws + o); o += (size_t)NN * HID / 2;
    ushort_t* inWt   = (ushort_t*)(ws + o); o += 128 * 64 / 2;
    ushort_t* Wlt    = (ushort_t*)(ws + o); o += 3 * 128 * 128 / 2;
    ushort_t* Wrt    = (ushort_t*)(ws + o); o += 3 * 128 * 128 / 2;
    int*      bsum   = (int*)(ws + o);      o += 256;
    int*      bbase  = (int*)(ws + o);      o += 256;
    // zero-init region (single memset)
    float*    zbase  = ws + o;
    float*    wsum   = ws + o;              o += NN;
    float*    ssum   = ws + o;              o += NSTORE * HID;
    int*      cnt    = (int*)(ws + o);      o += NN;
    int*      fill   = (int*)(ws + o);      o += NN;
    int*      scnt   = (int*)(ws + o);      o += 64;
    size_t zbytes = (size_t)(NN + NSTORE * HID + NN + NN + 64) * 4;

    hipMemsetAsync((void*)zbase, 0, zbytes, stream);

    const int EB = (EE + 255) / 256;
    const int TB = (ET + 255) / 256;
    const int WB = NN / 4;                    // wave-per-node kernels
    const int GB = (NN + 127) / 128;          // 128-row GEMM tiles

    k_cvt<<<(NN * 64 + 255) / 256, 256, 0, stream>>>(x, inW, gWl, gWr, xb, inWt, Wlt, Wrt);
    k_count<<<EB, 256, 0, stream>>>(ei, ew, cnt, wsum);
    k_psum<<<NBL, 256, 0, stream>>>(cnt, bsum);
    k_scanb<<<1, 256, 0, stream>>>(bsum, bbase, offs);
    k_offs<<<NBL, 256, 0, stream>>>(cnt, bbase, offs);
    k_scatter<<<TB, 256, 0, stream>>>(ei, ew, offs, cnt, wsum, fill, csrsrc, csr_ea);

    k_inproj<<<GB, 256, 0, stream>>>(xb, inWt, inb, ing, inbeta, h, hb, NN);

    for (int l = 0; l < 3; ++l) {
        dim3 gg(GB, 2);
        k_gemm2<<<gg, 256, 0, stream>>>(hb, Wlt + (size_t)l * HID * HID, Wrt + (size_t)l * HID * HID,
                                        gbl + l * HID, gbr + l * HID, xlb, xrb, NN);
        k_attn<<<WB, 256, 0, stream>>>(xlb, xrb, h, hb, offs, csrsrc, csr_ea,
                                       gWe + l * HID, gatt + l * HID, gbias + l * HID,
                                       blkg + l * HID, blkb + l * HID);
    }

    k_store_sum<<<120, 256, 0, stream>>>(h, smask, ssum, scnt);
    k_gate<<<NSTORE, 128, 0, stream>>>(ssum, scnt, ctxW, ctxb, gm);
    k_final<<<WB, 256, 0, stream>>>(h, smask, gm, fing, finb, out);
}

// Round 4
// 559.008 us; speedup vs baseline: 1.7332x; 1.1326x over previous
//
#include <hip/hip_runtime.h>
#include <math.h>

#define NN 50000
#define EE 800000
#define ET (EE + NN)
#define HID 128
#define NSTORE 50
#define NBL 196                      // ceil(NN/256)
#define CVT_B 12500                  // NN*64/256
#define CNT_B 3125                   // EE/256
#define SCT_B 3321                   // ceil(ET/256)
#define INP_B 391                    // ceil(NN/128)

typedef unsigned short ushort_t;
typedef unsigned long long u64;
typedef __attribute__((ext_vector_type(8))) short bf8;
typedef __attribute__((ext_vector_type(4))) float f4;
typedef __attribute__((ext_vector_type(4))) unsigned int u4;

__device__ __forceinline__ float b2f(ushort_t u) {
    union { unsigned int i; float f; } v; v.i = ((unsigned int)u) << 16; return v.f;
}
__device__ __forceinline__ ushort_t f2b(float f) {
    union { float f; unsigned int i; } v; v.f = f;
    unsigned int r = (v.i + 0x7fffu + ((v.i >> 16) & 1u)) >> 16;
    return (ushort_t)r;
}
__device__ __forceinline__ void b2f2(unsigned int u, float& lo, float& hi) {
    union { unsigned int i; float f; } a, c;
    a.i = u << 16; c.i = u & 0xffff0000u;
    lo = a.f; hi = c.f;
}
__device__ __forceinline__ unsigned int pk2(float lo, float hi) {
    return (unsigned int)f2b(lo) | ((unsigned int)f2b(hi) << 16);
}

// ---------------------------------------------------------------- build: bf16 cvt (BW) + edge count (latency), fused
// packed[dst]: bits 44+: degree count; bits 0..43: sum(ew) in 2^24 fixed point.
__global__ __launch_bounds__(256) void k_build(const float* __restrict__ x, const float* __restrict__ inW,
                                               const float* __restrict__ gWl, const float* __restrict__ gWr,
                                               const int* __restrict__ ei, const float* __restrict__ ew,
                                               ushort_t* __restrict__ xb, ushort_t* __restrict__ inWt,
                                               ushort_t* __restrict__ Wlt, ushort_t* __restrict__ Wrt,
                                               u64* __restrict__ packed, int* __restrict__ rank) {
    int b = blockIdx.x, t = threadIdx.x;
    if (b < CVT_B) {
        int i = b * 256 + t;
        xb[i] = f2b(x[i]);
        if (i < 128 * 64) {               // inWt[c*64+k] = inW[k*128+c]
            int c = i >> 6, k = i & 63;
            inWt[i] = f2b(inW[k * 128 + c]);
        }
        if (i < 3 * 128 * 128) {          // Wlt[l][n*128+k] = W[l][k*128+n]
            int l = i >> 14, r = i & 16383, nn2 = r >> 7, k = r & 127;
            Wlt[i] = f2b(gWl[(size_t)l * 16384 + k * 128 + nn2]);
            Wrt[i] = f2b(gWr[(size_t)l * 16384 + k * 128 + nn2]);
        }
    } else {
        int i = (b - CVT_B) * 256 + t;
        if (i < EE) {
            int dst = ei[EE + i];
            unsigned int wfix = __float2uint_rn(ew[i] * 16777216.0f);
            u64 old = atomicAdd(&packed[dst], (1ULL << 44) | (u64)wfix);
            rank[i] = (int)(old >> 44);
        }
    }
}

// per-256-chunk sums of (deg+1)
__global__ __launch_bounds__(256) void k_psum(const u64* __restrict__ packed, int* __restrict__ bsum) {
    int t = threadIdx.x, bidx = blockIdx.x;
    int i = bidx * 256 + t;
    int v = (i < NN) ? (int)(packed[i] >> 44) + 1 : 0;
#pragma unroll
    for (int d = 1; d < 64; d <<= 1) v += __shfl_xor(v, d);
    __shared__ int ws4[4];
    if ((t & 63) == 0) ws4[t >> 6] = v;
    __syncthreads();
    if (t == 0) bsum[bidx] = ws4[0] + ws4[1] + ws4[2] + ws4[3];
}

__global__ __launch_bounds__(256) void k_scanb(const int* __restrict__ bsum,
                                               int* __restrict__ bbase, int* __restrict__ offs) {
    __shared__ int s[256];
    int t = threadIdx.x;
    int v = (t < NBL) ? bsum[t] : 0;
    s[t] = v;
    __syncthreads();
    for (int d = 1; d < 256; d <<= 1) {
        int u = (t >= d) ? s[t - d] : 0;
        __syncthreads();
        s[t] += u;
        __syncthreads();
    }
    if (t < NBL) bbase[t] = s[t] - v;    // exclusive base
    if (t == 0) offs[NN] = ET;
}

__global__ __launch_bounds__(256) void k_offs(const u64* __restrict__ packed,
                                              const int* __restrict__ bbase, int* __restrict__ offs) {
    __shared__ int wsum4[4];
    int t = threadIdx.x, bidx = blockIdx.x;
    int i = bidx * 256 + t;
    int v = (i < NN) ? (int)(packed[i] >> 44) + 1 : 0;
    int lane = t & 63, w = t >> 6;
    int sc = v;
#pragma unroll
    for (int d = 1; d < 64; d <<= 1) {
        int u = __shfl_up(sc, d);
        if (lane >= d) sc += u;
    }
    if (lane == 63) wsum4[w] = sc;
    __syncthreads();
    int wo = 0;
    for (int k = 0; k < w; ++k) wo += wsum4[k];
    if (i < NN) offs[i] = bbase[bidx] + wo + sc - v;
}

// ---------------------------------------------------------------- scatter (no atomics) + input proj, fused
__global__ __launch_bounds__(256) void k_scat_inproj(
        const int* __restrict__ ei, const float* __restrict__ ew,
        const int* __restrict__ offs, const u64* __restrict__ packed,
        const int* __restrict__ rank, int2* __restrict__ csr,
        const ushort_t* __restrict__ A, const ushort_t* __restrict__ Wt,
        const float* __restrict__ bias, const float* __restrict__ g,
        const float* __restrict__ be, float* __restrict__ h,
        ushort_t* __restrict__ hb) {
    __shared__ float s1[2][128], s2[2][128];
    if (blockIdx.x < SCT_B) {
        int i = blockIdx.x * 256 + threadIdx.x;
        if (i < EE) {
            int src = ei[i], dst = ei[EE + i];
            int pos = offs[dst] + rank[i];
            int2 v; v.x = src; v.y = __float_as_int(ew[i]);
            csr[pos] = v;
        } else if (i < ET) {
            int nd = i - EE;
            u64 p = packed[nd];
            int deg = (int)(p >> 44);
            float ws = (float)(p & ((1ULL << 44) - 1)) * (1.0f / 16777216.0f);
            float la = ws / fmaxf((float)deg, 1.0f);
            int pos = offs[nd + 1] - 1;
            int2 v; v.x = nd; v.y = __float_as_int(la);
            csr[pos] = v;
        }
        return;
    }
    // ---- input projection: GELU(xb@inWt^T + b) then LN, K=64
    const int K = 64;
    int bidx = blockIdx.x - SCT_B;
    int lane = threadIdx.x & 63, w = threadIdx.x >> 6;
    int rw = w >> 1, cw = w & 1;
    int q = lane >> 4, l16 = lane & 15;
    int row0 = bidx * 128 + rw * 64;
    int col0 = cw * 64;
    bf8 z; for (int t = 0; t < 8; ++t) z[t] = 0;

    bf8 bfr[2][4];
#pragma unroll
    for (int kk = 0; kk < 2; ++kk)
#pragma unroll
        for (int j = 0; j < 4; ++j)
            bfr[kk][j] = *(const bf8*)(Wt + (size_t)(col0 + j * 16 + l16) * K + kk * 32 + q * 8);

    f4 acc[4][4];
#pragma unroll
    for (int i = 0; i < 4; ++i)
#pragma unroll
        for (int j = 0; j < 4; ++j) acc[i][j] = (f4)(0.f);

#pragma unroll
    for (int kk = 0; kk < 2; ++kk) {
        bf8 af[4];
#pragma unroll
        for (int i = 0; i < 4; ++i) {
            int r = row0 + i * 16 + l16;
            af[i] = (r < NN) ? *(const bf8*)(A + (size_t)r * K + kk * 32 + q * 8) : z;
        }
#pragma unroll
        for (int i = 0; i < 4; ++i)
#pragma unroll
            for (int j = 0; j < 4; ++j)
                acc[i][j] = __builtin_amdgcn_mfma_f32_16x16x32_bf16(af[i], bfr[kk][j], acc[i][j], 0, 0, 0);
    }
#pragma unroll
    for (int i = 0; i < 4; ++i) {
#pragma unroll
        for (int j = 0; j < 4; ++j) {
            float bv = bias[col0 + j * 16 + l16];
#pragma unroll
            for (int r = 0; r < 4; ++r) {
                float v = acc[i][j][r] + bv;
                v = 0.5f * v * (1.f + erff(v * 0.70710678118654752f));
                acc[i][j][r] = v;
            }
        }
    }
#pragma unroll
    for (int i = 0; i < 4; ++i) {
#pragma unroll
        for (int r = 0; r < 4; ++r) {
            float sm = acc[i][0][r] + acc[i][1][r] + acc[i][2][r] + acc[i][3][r];
            float sq = acc[i][0][r] * acc[i][0][r] + acc[i][1][r] * acc[i][1][r]
                     + acc[i][2][r] * acc[i][2][r] + acc[i][3][r] * acc[i][3][r];
#pragma unroll
            for (int k = 1; k < 16; k <<= 1) { sm += __shfl_xor(sm, k); sq += __shfl_xor(sq, k); }
            if (l16 == 0) {
                int rl = rw * 64 + i * 16 + q * 4 + r;
                s1[cw][rl] = sm; s2[cw][rl] = sq;
            }
        }
    }
    __syncthreads();
#pragma unroll
    for (int i = 0; i < 4; ++i) {
#pragma unroll
        for (int r = 0; r < 4; ++r) {
            int rl = rw * 64 + i * 16 + q * 4 + r;
            int gr = bidx * 128 + rl;
            if (gr >= NN) continue;
            float sm = s1[0][rl] + s1[1][rl];
            float sq = s2[0][rl] + s2[1][rl];
            float mu = sm * (1.f / 128.f);
            float var = sq * (1.f / 128.f) - mu * mu;
            float rinv = rsqrtf(var + 1e-5f);
#pragma unroll
            for (int j = 0; j < 4; ++j) {
                int gc = col0 + j * 16 + l16;
                float v = (acc[i][j][r] - mu) * rinv * g[gc] + be[gc];
                h[(size_t)gr * HID + gc] = v;
                hb[(size_t)gr * HID + gc] = f2b(v);
            }
        }
    }
}

// ---------------------------------------------------------------- bf16 MFMA dual GEMM (K=128)
__global__ __launch_bounds__(256) void k_gemm2(const ushort_t* __restrict__ A,
                                               const ushort_t* __restrict__ Wt0,
                                               const ushort_t* __restrict__ Wt1,
                                               const float* __restrict__ b0,
                                               const float* __restrict__ b1,
                                               ushort_t* __restrict__ o0,
                                               ushort_t* __restrict__ o1, int n) {
    const int K = 128;
    const ushort_t* Wt = blockIdx.y ? Wt1 : Wt0;
    const float* bias = blockIdx.y ? b1 : b0;
    ushort_t* outb = blockIdx.y ? o1 : o0;
    int lane = threadIdx.x & 63, w = threadIdx.x >> 6;
    int rw = w >> 1, cw = w & 1;
    int q = lane >> 4, l16 = lane & 15;
    int row0 = blockIdx.x * 128 + rw * 64;
    int col0 = cw * 64;
    bf8 z; for (int t = 0; t < 8; ++t) z[t] = 0;

    bf8 bfr[4][4];
#pragma unroll
    for (int kk = 0; kk < 4; ++kk)
#pragma unroll
        for (int j = 0; j < 4; ++j)
            bfr[kk][j] = *(const bf8*)(Wt + (size_t)(col0 + j * 16 + l16) * K + kk * 32 + q * 8);

    f4 acc[4][4];
#pragma unroll
    for (int i = 0; i < 4; ++i)
#pragma unroll
        for (int j = 0; j < 4; ++j) acc[i][j] = (f4)(0.f);

#pragma unroll
    for (int kk = 0; kk < 4; ++kk) {
        bf8 af[4];
#pragma unroll
        for (int i = 0; i < 4; ++i) {
            int r = row0 + i * 16 + l16;
            af[i] = (r < n) ? *(const bf8*)(A + (size_t)r * K + kk * 32 + q * 8) : z;
        }
#pragma unroll
        for (int i = 0; i < 4; ++i)
#pragma unroll
            for (int j = 0; j < 4; ++j)
                acc[i][j] = __builtin_amdgcn_mfma_f32_16x16x32_bf16(af[i], bfr[kk][j], acc[i][j], 0, 0, 0);
    }
#pragma unroll
    for (int i = 0; i < 4; ++i) {
        int gr0 = row0 + i * 16 + q * 4;
#pragma unroll
        for (int j = 0; j < 4; ++j) {
            int gc = col0 + j * 16 + l16;
            float bv = bias[gc];
#pragma unroll
            for (int r = 0; r < 4; ++r) {
                int gr = gr0 + r;
                if (gr < n) outb[(size_t)gr * HID + gc] = f2b(acc[i][j][r] + bv);
            }
        }
    }
}

// ---------------------------------------------------------------- GATv2 attention
// wave per dst node; 16 lanes = one edge (lane = head, DH=8 in-lane); 4 edges/step.
__global__ __launch_bounds__(256) void k_attn(const ushort_t* __restrict__ xl,
                                              const ushort_t* __restrict__ xr,
                                              float* __restrict__ h,
                                              ushort_t* __restrict__ hb,
                                              const int* __restrict__ offs,
                                              const int2* __restrict__ csr,
                                              const float* __restrict__ We,
                                              const float* __restrict__ att,
                                              const float* __restrict__ gbias,
                                              const float* __restrict__ g,
                                              const float* __restrict__ b) {
    int wid = (blockIdx.x * 256 + threadIdx.x) >> 6;
    int lane = threadIdx.x & 63;
    if (wid >= NN) return;
    int hd = lane & 15;          // head index (16 heads; DH=8 in-lane)
    int grp = lane >> 4;         // edge subgroup 0..3
    int dbase = hd * 8;
    size_t base = (size_t)wid * HID;

    float xr8[8], at8[8], we8[8];
    {
        u4 uxr = *(const u4*)(xr + base + dbase);
        b2f2(uxr.x, xr8[0], xr8[1]); b2f2(uxr.y, xr8[2], xr8[3]);
        b2f2(uxr.z, xr8[4], xr8[5]); b2f2(uxr.w, xr8[6], xr8[7]);
        f4 a0 = *(const f4*)(att + dbase), a1 = *(const f4*)(att + dbase + 4);
        at8[0] = a0.x; at8[1] = a0.y; at8[2] = a0.z; at8[3] = a0.w;
        at8[4] = a1.x; at8[5] = a1.y; at8[6] = a1.z; at8[7] = a1.w;
        f4 w0 = *(const f4*)(We + dbase), w1 = *(const f4*)(We + dbase + 4);
        we8[0] = w0.x; we8[1] = w0.y; we8[2] = w0.z; we8[3] = w0.w;
        we8[4] = w1.x; we8[5] = w1.y; we8[6] = w1.z; we8[7] = w1.w;
    }
    int p0 = offs[wid], p1 = offs[wid + 1];
    float Z = 0.f;
    float acc[8];
#pragma unroll
    for (int q = 0; q < 8; ++q) acc[q] = 0.f;

#define QUAD(EJ, MASKED)                                                        \
    {                                                                           \
        int ei_ = (EJ) + grp;                                                   \
        int s_ = __shfl(sv, ei_);                                               \
        float ea_ = __shfl(evl, ei_);                                           \
        bool val_ = MASKED ? (ei_ < mm) : true;                                 \
        u4 ux_ = *(const u4*)(xl + (size_t)s_ * HID + dbase);                   \
        float x_[8];                                                            \
        b2f2(ux_.x, x_[0], x_[1]); b2f2(ux_.y, x_[2], x_[3]);                   \
        b2f2(ux_.z, x_[4], x_[5]); b2f2(ux_.w, x_[6], x_[7]);                   \
        float lg_ = 0.f;                                                        \
        _Pragma("unroll")                                                       \
        for (int q_ = 0; q_ < 8; ++q_) {                                        \
            float t_ = x_[q_] + xr8[q_] + ea_ * we8[q_];                        \
            t_ = (t_ > 0.f) ? t_ : 0.2f * t_;                                   \
            lg_ = fmaf(at8[q_], t_, lg_);                                       \
        }                                                                       \
        float w_ = val_ ? __expf(lg_) : 0.f;                                    \
        Z += w_;                                                                \
        _Pragma("unroll")                                                       \
        for (int q_ = 0; q_ < 8; ++q_) acc[q_] = fmaf(w_, x_[q_], acc[q_]);     \
    }

    for (int cb = p0; cb < p1; cb += 64) {
        int mm = min(64, p1 - cb);
        int2 m2 = (lane < mm) ? csr[cb + lane] : make_int2(0, 0);
        int sv = m2.x;
        float evl = __int_as_float(m2.y);
        int j = 0;
        for (; j + 8 <= mm; j += 8) { QUAD(j, false) QUAD(j + 4, false) }
        for (; j < mm; j += 4) QUAD(j, true)
    }
#undef QUAD

    // combine the 4 edge subgroups
    Z += __shfl_xor(Z, 16); Z += __shfl_xor(Z, 32);
#pragma unroll
    for (int q = 0; q < 8; ++q) {
        acc[q] += __shfl_xor(acc[q], 16);
        acc[q] += __shfl_xor(acc[q], 32);
    }
    float inv = 1.f / (Z + 1e-16f);

    // residual + LN over the 128 dims held by the 16 head-lanes
    f4 hv0 = *(const f4*)(h + base + dbase);
    f4 hv1 = *(const f4*)(h + base + dbase + 4);
    float hres[8] = {hv0.x, hv0.y, hv0.z, hv0.w, hv1.x, hv1.y, hv1.z, hv1.w};
    f4 gb0 = *(const f4*)(gbias + dbase), gb1 = *(const f4*)(gbias + dbase + 4);
    float gb8[8] = {gb0.x, gb0.y, gb0.z, gb0.w, gb1.x, gb1.y, gb1.z, gb1.w};
    float o[8], sm = 0.f, sq = 0.f;
#pragma unroll
    for (int q = 0; q < 8; ++q) {
        o[q] = acc[q] * inv + gb8[q] + hres[q];
        sm += o[q]; sq += o[q] * o[q];
    }
#pragma unroll
    for (int k = 1; k < 16; k <<= 1) { sm += __shfl_xor(sm, k); sq += __shfl_xor(sq, k); }
    float mu = sm * (1.f / 128.f);
    float var = sq * (1.f / 128.f) - mu * mu;
    float rinv = rsqrtf(var + 1e-5f);
    f4 g0 = *(const f4*)(g + dbase), g1 = *(const f4*)(g + dbase + 4);
    float g8[8] = {g0.x, g0.y, g0.z, g0.w, g1.x, g1.y, g1.z, g1.w};
    f4 b0 = *(const f4*)(b + dbase), b1 = *(const f4*)(b + dbase + 4);
    float b8[8] = {b0.x, b0.y, b0.z, b0.w, b1.x, b1.y, b1.z, b1.w};
    float v8[8];
#pragma unroll
    for (int q = 0; q < 8; ++q) v8[q] = (o[q] - mu) * rinv * g8[q] + b8[q];
    if (grp == 0) {
        f4 s0 = {v8[0], v8[1], v8[2], v8[3]};
        f4 s1 = {v8[4], v8[5], v8[6], v8[7]};
        *(f4*)(h + base + dbase) = s0;
        *(f4*)(h + base + dbase + 4) = s1;
        u4 hu;
        hu.x = pk2(v8[0], v8[1]); hu.y = pk2(v8[2], v8[3]);
        hu.z = pk2(v8[4], v8[5]); hu.w = pk2(v8[6], v8[7]);
        *(u4*)(hb + base + dbase) = hu;
    }
}

// ---------------------------------------------------------------- per-store segment sum
__global__ __launch_bounds__(256) void k_store_sum(const float* __restrict__ h,
                                                   const int* __restrict__ mask,
                                                   float* __restrict__ ssum,
                                                   int* __restrict__ scnt) {
    __shared__ float ls[NSTORE * HID];
    __shared__ int lc[NSTORE];
    int t = threadIdx.x;
    for (int i = t; i < NSTORE * HID; i += 256) ls[i] = 0.f;
    if (t < NSTORE) lc[t] = 0;
    __syncthreads();
    int wid = blockIdx.x * 4 + (t >> 6);
    int lane = t & 63;
    int nw = gridDim.x * 4;
    int d0 = lane * 2, d1 = d0 + 1;
    for (int node = wid; node < NN; node += nw) {
        int s = mask[node];
        size_t base = (size_t)node * HID;
        atomicAdd(&ls[s * HID + d0], h[base + d0]);
        atomicAdd(&ls[s * HID + d1], h[base + d1]);
        if (lane == 0) atomicAdd(&lc[s], 1);
    }
    __syncthreads();
    for (int i = t; i < NSTORE * HID; i += 256) atomicAdd(&ssum[i], ls[i]);
    if (t < NSTORE) atomicAdd(&scnt[t], lc[t]);
}

// ---------------------------------------------------------------- gate
__global__ __launch_bounds__(128) void k_gate(const float* __restrict__ ssum,
                                              const int* __restrict__ scnt,
                                              const float* __restrict__ ctxW,
                                              const float* __restrict__ ctxb,
                                              float* __restrict__ gm) {
    __shared__ float mloc[HID];
    int s = blockIdx.x, t = threadIdx.x;
    float c = fmaxf((float)scnt[s], 1.f);
    float mk = ssum[s * HID + t] / c;
    mloc[t] = mk;
    __syncthreads();
    float acc = ctxb[t];
    for (int j = 0; j < HID; ++j) acc += mloc[j] * ctxW[j * HID + t];
    float gate = 1.f / (1.f + __expf(-acc));
    gm[s * HID + t] = gate * mk;
}

// ---------------------------------------------------------------- final: out = LN(h + gm[store])
__global__ __launch_bounds__(256) void k_final(const float* __restrict__ h,
                                               const int* __restrict__ mask,
                                               const float* __restrict__ gm,
                                               const float* __restrict__ g,
                                               const float* __restrict__ b,
                                               float* __restrict__ out) {
    int wid = (blockIdx.x * 256 + threadIdx.x) >> 6;
    int lane = threadIdx.x & 63;
    if (wid >= NN) return;
    size_t base = (size_t)wid * HID;
    int s = mask[wid];
    int d0 = lane * 2, d1 = d0 + 1;
    float v0 = h[base + d0] + gm[s * HID + d0];
    float v1 = h[base + d1] + gm[s * HID + d1];
    float sm = v0 + v1, sq = v0 * v0 + v1 * v1;
#pragma unroll
    for (int k = 1; k < 64; k <<= 1) { sm += __shfl_xor(sm, k); sq += __shfl_xor(sq, k); }
    float mu = sm * (1.f / 128.f);
    float var = sq * (1.f / 128.f) - mu * mu;
    float r = rsqrtf(var + 1e-5f);
    out[base + d0] = (v0 - mu) * r * g[d0] + b[d0];
    out[base + d1] = (v1 - mu) * r * g[d1] + b[d1];
}

// ---------------------------------------------------------------- launch
extern "C" void kernel_launch(void* const* d_in, const int* in_sizes, int n_in,
                              void* d_out, int out_size, void* d_ws, size_t ws_size,
                              hipStream_t stream) {
    const float* x      = (const float*)d_in[0];
    const int*   ei     = (const int*)d_in[1];
    const float* ew     = (const float*)d_in[2];
    const int*   smask  = (const int*)d_in[3];
    const float* inW    = (const float*)d_in[4];
    const float* inb    = (const float*)d_in[5];
    const float* ing    = (const float*)d_in[6];
    const float* inbeta = (const float*)d_in[7];
    const float* gWl    = (const float*)d_in[8];
    const float* gbl    = (const float*)d_in[9];
    const float* gWr    = (const float*)d_in[10];
    const float* gbr    = (const float*)d_in[11];
    const float* gWe    = (const float*)d_in[12];
    const float* gatt   = (const float*)d_in[13];
    const float* gbias  = (const float*)d_in[14];
    const float* blkg   = (const float*)d_in[15];
    const float* blkb   = (const float*)d_in[16];
    const float* ctxW   = (const float*)d_in[17];
    const float* ctxb   = (const float*)d_in[18];
    const float* fing   = (const float*)d_in[19];
    const float* finb   = (const float*)d_in[20];
    float* out = (float*)d_out;

    float* ws = (float*)d_ws;
    size_t o = 0;
    float*    h      = ws + o;              o += (size_t)NN * HID;
    int2*     csr    = (int2*)(ws + o);     o += (size_t)ET * 2;
    float*    gm     = ws + o;              o += NSTORE * HID;
    int*      offs   = (int*)(ws + o);      o += 50004;
    int*      rank   = (int*)(ws + o);      o += EE;
    ushort_t* xb     = (ushort_t*)(ws + o); o += (size_t)NN * 64 / 2;
    ushort_t* hb     = (ushort_t*)(ws + o); o += (size_t)NN * HID / 2;
    ushort_t* xlb    = (ushort_t*)(ws + o); o += (size_t)NN * HID / 2;
    ushort_t* xrb    = (ushort_t*)(ws + o); o += (size_t)NN * HID / 2;
    ushort_t* inWt   = (ushort_t*)(ws + o); o += 128 * 64 / 2;
    ushort_t* Wlt    = (ushort_t*)(ws + o); o += 3 * 128 * 128 / 2;
    ushort_t* Wrt    = (ushort_t*)(ws + o); o += 3 * 128 * 128 / 2;
    int*      bsum   = (int*)(ws + o);      o += 256;
    int*      bbase  = (int*)(ws + o);      o += 256;
    // zero-init region (single memset); packed must be 8B-aligned (o is even here)
    if (o & 1) ++o;
    float*    zbase  = ws + o;
    u64*      packed = (u64*)(ws + o);      o += (size_t)NN * 2;
    float*    ssum   = ws + o;              o += NSTORE * HID;
    int*      scnt   = (int*)(ws + o);      o += 64;
    size_t zbytes = (size_t)(NN * 2 + NSTORE * HID + 64) * 4;

    hipMemsetAsync((void*)zbase, 0, zbytes, stream);

    const int WB = NN / 4;                    // wave-per-node kernels
    const int GB = (NN + 127) / 128;          // 128-row GEMM tiles

    k_build<<<CVT_B + CNT_B, 256, 0, stream>>>(x, inW, gWl, gWr, ei, ew,
                                               xb, inWt, Wlt, Wrt, packed, rank);
    k_psum<<<NBL, 256, 0, stream>>>(packed, bsum);
    k_scanb<<<1, 256, 0, stream>>>(bsum, bbase, offs);
    k_offs<<<NBL, 256, 0, stream>>>(packed, bbase, offs);
    k_scat_inproj<<<SCT_B + INP_B, 256, 0, stream>>>(ei, ew, offs, packed, rank, csr,
                                                     xb, inWt, inb, ing, inbeta, h, hb);

    for (int l = 0; l < 3; ++l) {
        dim3 gg(GB, 2);
        k_gemm2<<<gg, 256, 0, stream>>>(hb, Wlt + (size_t)l * HID * HID, Wrt + (size_t)l * HID * HID,
                                        gbl + l * HID, gbr + l * HID, xlb, xrb, NN);
        k_attn<<<WB, 256, 0, stream>>>(xlb, xrb, h, hb, offs, csr,
                                       gWe + l * HID, gatt + l * HID, gbias + l * HID,
                                       blkg + l * HID, blkb + l * HID);
    }

    k_store_sum<<<120, 256, 0, stream>>>(h, smask, ssum, scnt);
    k_gate<<<NSTORE, 128, 0, stream>>>(ssum, scnt, ctxW, ctxb, gm);
    k_final<<<WB, 256, 0, stream>>>(h, smask, gm, fing, finb, out);
}